// Round 10
// baseline (731.429 us; speedup 1.0000x reference)
//
#include <hip/hip_runtime.h>
#include <math.h>
#include <limits.h>

#define DIM 2048
#define NEXP 256
#define TOPK 8
#define BM 16
#define BK 16
#define NTH 256
#define NTILE 128

// np-einsum fp32 replica (LOCKED by R3/R4/R6/R8 passes — do not perturb):
//   4 partial chains per output, chain j takes k ≡ j (mod 4);
//   k in 16-groups ascending, within group chunk order 3,2,1,0;
//   separate mul/add rounding (no fma); hadd tree (l0+l1)+(l2+l3);
//   sigmoid in f64 -> f32; pairwise-8 weight sum; ties -> lower index.
// v_pk_*_f32 = element-wise IEEE f32 (bit-identical, halves issue slots).
// R10: x is wave-exclusive + wave-uniform-addressed -> read x directly from
// global (same-address lanes, L1 broadcast, vmcnt pipe); LDS carries ONLY the
// lane-distinct w reads (16 ds_read_b128/tile/wave). LDS pipe ~164us < VALU
// 218us. R9 lesson: counted-vmcnt/manual barriers don't pay here — plain
// __syncthreads double-buffer.

typedef float f32x2 __attribute__((ext_vector_type(2)));

__device__ __forceinline__ f32x2 pkmul(f32x2 a, f32x2 b) {
    f32x2 d;
    asm("v_pk_mul_f32 %0, %1, %2" : "=v"(d) : "v"(a), "v"(b));
    return d;
}
__device__ __forceinline__ f32x2 pkadd(f32x2 a, f32x2 b) {
    f32x2 d;
    asm("v_pk_add_f32 %0, %1, %2" : "=v"(d) : "v"(a), "v"(b));
    return d;
}

__device__ __forceinline__ void gload16(const void* gptr, void* lptr) {
    __builtin_amdgcn_global_load_lds(
        (const __attribute__((address_space(1))) unsigned int*)(unsigned long long)gptr,
        (__attribute__((address_space(3))) unsigned int*)(unsigned int)(unsigned long long)lptr,
        16, 0, 0);
}

__global__ __launch_bounds__(NTH) void gate_kernel(
    const float* __restrict__ x, const float* __restrict__ w,
    const float* __restrict__ bias, float* __restrict__ outw,
    float* __restrict__ outi)
{
#pragma clang fp contract(off)
    // wbuf[buf]: float idx (c*256 + e)*4 + j  (chunk c=0..3, expert e, j=k%4)
    __shared__ float wbuf[2][4096];   // 32 KB total LDS

    const int tid   = threadIdx.x;
    const int elane = tid & 63;              // experts elane + 64*i
    const int r0    = (tid >> 6) * 4;        // wave-exclusive 4 rows
    const int gr    = blockIdx.x * BM;

    const char* wsrc = (const char*)w + (size_t)tid * (DIM * 4);  // expert row `tid`
    // wave-uniform x row pointers (4 rows, 8 KB apart)
    const char* xrow0 = (const char*)x + (size_t)(gr + r0) * (DIM * 4);

    auto stage_w = [&](int buf, int kt) {
        const size_t kb = (size_t)kt * 64;   // 16 floats = 64 B per tile
        char* dst = (char*)&wbuf[buf][0] + tid * 16;
        gload16(wsrc + kb,      dst);
        gload16(wsrc + kb + 16, dst + 4096);
        gload16(wsrc + kb + 32, dst + 8192);
        gload16(wsrc + kb + 48, dst + 12288);
    };

    // acc[r][i][p]: p=0 -> chains (j0,j1), p=1 -> chains (j2,j3)
    f32x2 acc[4][4][2];
#pragma unroll
    for (int r = 0; r < 4; ++r)
#pragma unroll
        for (int i = 0; i < 4; ++i)
#pragma unroll
            for (int p = 0; p < 2; ++p) acc[r][i][p] = (f32x2){0.0f, 0.0f};

    auto compute = [&](int buf, int kt) {
        const char* xt = xrow0 + (size_t)kt * 64;   // this tile's x (global)
#pragma unroll
        for (int c = 3; c >= 0; --c) {          // reversed chunk order in 16-group
            f32x2 xlo[4], xhi[4];
#pragma unroll
            for (int r = 0; r < 4; ++r) {
                // wave-uniform address: one line, L1 broadcast (vmcnt pipe)
                const float4 xv = *(const float4*)(xt + r * (DIM * 4) + c * 16);
                xlo[r] = (f32x2){xv.x, xv.y};
                xhi[r] = (f32x2){xv.z, xv.w};
            }
#pragma unroll
            for (int i = 0; i < 4; ++i) {
                const float4 wv = *(const float4*)&wbuf[buf][(c * 256 + elane + 64 * i) * 4];
                const f32x2 wlo = (f32x2){wv.x, wv.y};
                const f32x2 whi = (f32x2){wv.z, wv.w};
#pragma unroll
                for (int r = 0; r < 4; ++r) {
                    acc[r][i][0] = pkadd(acc[r][i][0], pkmul(xlo[r], wlo));
                    acc[r][i][1] = pkadd(acc[r][i][1], pkmul(xhi[r], whi));
                }
            }
        }
    };

    // ---- main loop: double-buffered w staging, x streamed from global ----
    stage_w(0, 0);
    __syncthreads();
    for (int kt = 0; kt < NTILE; ++kt) {
        const int buf = kt & 1;
        if (kt + 1 < NTILE) stage_w(buf ^ 1, kt + 1);
        compute(buf, kt);
        __syncthreads();
    }

    // ---- epilogue: hadd tree + f64 sigmoid -> scores in wbuf[0] ----
    float* sc = &wbuf[0][0];                 // [16][256] = 16 KB (exact fit)
#pragma unroll
    for (int r = 0; r < 4; ++r)
#pragma unroll
        for (int i = 0; i < 4; ++i) {
            const float l01 = acc[r][i][0].x + acc[r][i][0].y;
            const float l23 = acc[r][i][1].x + acc[r][i][1].y;
            const float logit = l01 + l23;
            const double s = 1.0 / (1.0 + exp(-(double)logit));
            sc[(r0 + r) * NEXP + (elane + 64 * i)] = (float)s;
        }
    __syncthreads();

    float* cval = &wbuf[1][0];               // [16][64]
    int*   cidx = (int*)&wbuf[1][1024];      // [16][64]

    // ---- per-row top-8: 8 subs/row on first 128 threads ----
    if (tid < 128) {
        const int row = tid >> 3;
        const int sub = tid & 7;
        float tv[TOPK];
        int   ti[TOPK];
#pragma unroll
        for (int q = 0; q < TOPK; ++q) { tv[q] = -INFINITY; ti[q] = INT_MAX; }
        for (int j = 0; j < 32; ++j) {
            const int e = sub + (j << 3);    // ascending index => stable
            const float v = sc[row * NEXP + e] + bias[e];
            if (v > tv[TOPK - 1]) {
                int p = TOPK - 1;
                while (p > 0 && v > tv[p - 1]) {
                    tv[p] = tv[p - 1]; ti[p] = ti[p - 1]; --p;
                }
                tv[p] = v; ti[p] = e;
            }
        }
#pragma unroll
        for (int q = 0; q < TOPK; ++q) {
            cval[row * 64 + sub * 8 + q] = tv[q];
            cidx[row * 64 + sub * 8 + q] = ti[q];
        }
    }
    __syncthreads();

    // ---- leaders merge 8 sorted lists; ties -> lower index; output ----
    if (tid < 128 && (tid & 7) == 0) {
        const int row = tid >> 3;
        int p[8];
#pragma unroll
        for (int s = 0; s < 8; ++s) p[s] = 0;
        float g[TOPK];
        int   sel[TOPK];
        for (int k = 0; k < TOPK; ++k) {
            float best = -INFINITY;
            int bidx = INT_MAX;
            int bs = 0;
            for (int s = 0; s < 8; ++s) {
                if (p[s] < 8) {
                    const float v = cval[row * 64 + s * 8 + p[s]];
                    const int  id = cidx[row * 64 + s * 8 + p[s]];
                    if (v > best || (v == best && id < bidx)) {
                        best = v; bidx = id; bs = s;
                    }
                }
            }
            p[bs]++;
            sel[k] = bidx;
            g[k] = sc[row * NEXP + bidx];    // original score (no bias)
        }
        const float s01 = g[0] + g[1], s23 = g[2] + g[3];
        const float s45 = g[4] + g[5], s67 = g[6] + g[7];
        const float wsum = (s01 + s23) + (s45 + s67);
        const float den = wsum + 1e-20f;
        const size_t orow = (size_t)(gr + row) * TOPK;
#pragma unroll
        for (int k = 0; k < TOPK; ++k) {
            outw[orow + k] = (g[k] / den) * 2.5f;
            outi[orow + k] = (float)sel[k];
        }
    }
}

extern "C" void kernel_launch(void* const* d_in, const int* in_sizes, int n_in,
                              void* d_out, int out_size, void* d_ws, size_t ws_size,
                              hipStream_t stream) {
    const float* x    = (const float*)d_in[0];
    const float* w    = (const float*)d_in[1];
    const float* bias = (const float*)d_in[2];
    float* outw = (float*)d_out;
    const int M = in_sizes[0] / DIM;              // 16384 rows
    float* outi = outw + (size_t)M * TOPK;
    const int grid = M / BM;                      // 1024 blocks
    hipLaunchKernelGGL(gate_kernel, dim3(grid), dim3(NTH), 0, stream,
                       x, w, bias, outw, outi);
}

// Round 11
// 414.300 us; speedup vs baseline: 1.7655x; 1.7655x over previous
//
#include <hip/hip_runtime.h>
#include <math.h>
#include <limits.h>

#define DIM 2048
#define NEXP 256
#define TOPK 8
#define BM 16
#define BK 16
#define NTH 256
#define NTILE 128

// np-einsum fp32 replica (LOCKED by R3/R4/R6/R8 passes — do not perturb):
//   4 partial chains per output, chain j takes k ≡ j (mod 4);
//   k in 16-groups ascending, within group chunk order 3,2,1,0;
//   separate mul/add rounding (no fma); hadd tree (l0+l1)+(l2+l3);
//   sigmoid in f64 -> f32; pairwise-8 weight sum; ties -> lower index.
// v_pk_*_f32 = element-wise IEEE f32 (bit-identical, halves issue slots).
// Structure = R8 (best: 464us): x+w both LDS-staged, plain __syncthreads
// double-buffer. R9 lesson: counted vmcnt loses. R10 lesson: x from global
// without prefetch distance stalls. R11: + s_setprio around pk bursts (T5;
// 4 independent blocks/CU = wave role diversity regime).

typedef float f32x2 __attribute__((ext_vector_type(2)));

__device__ __forceinline__ f32x2 pkmul(f32x2 a, f32x2 b) {
    f32x2 d;
    asm("v_pk_mul_f32 %0, %1, %2" : "=v"(d) : "v"(a), "v"(b));
    return d;
}
__device__ __forceinline__ f32x2 pkadd(f32x2 a, f32x2 b) {
    f32x2 d;
    asm("v_pk_add_f32 %0, %1, %2" : "=v"(d) : "v"(a), "v"(b));
    return d;
}

__device__ __forceinline__ void gload16(const void* gptr, void* lptr) {
    __builtin_amdgcn_global_load_lds(
        (const __attribute__((address_space(1))) unsigned int*)(unsigned long long)gptr,
        (__attribute__((address_space(3))) unsigned int*)(unsigned int)(unsigned long long)lptr,
        16, 0, 0);
}

__global__ __launch_bounds__(NTH) void gate_kernel(
    const float* __restrict__ x, const float* __restrict__ w,
    const float* __restrict__ bias, float* __restrict__ outw,
    float* __restrict__ outi)
{
#pragma clang fp contract(off)
    // wbuf[buf]: float idx (c*256 + e)*4 + j  (chunk c=0..3, expert e, j=k%4)
    __shared__ float wbuf[2][4096];   // 32 KB
    __shared__ float xbuf[2][256];    // 2 KB  [row*16 + k]

    const int tid   = threadIdx.x;
    const int elane = tid & 63;              // experts elane + 64*i
    const int r0    = (tid >> 6) * 4;        // 4 rows per thread
    const int gr    = blockIdx.x * BM;

    const char* wbase = (const char*)w + (size_t)tid * (DIM * 4);   // expert row `tid`
    const int xrow = tid >> 2, xq = tid & 3;                        // tid<64 stages x
    const char* xbase = (const char*)x + ((size_t)(gr + xrow) * DIM + xq * 4) * 4;

    auto stage = [&](int buf, int kt) {
        const size_t kb = (size_t)kt * 64;   // 16 floats = 64 B per tile
        char* dst = (char*)&wbuf[buf][0] + tid * 16;
        gload16(wbase + kb,      dst);
        gload16(wbase + kb + 16, dst + 4096);
        gload16(wbase + kb + 32, dst + 8192);
        gload16(wbase + kb + 48, dst + 12288);
        if (tid < 64)
            gload16(xbase + kb, (char*)&xbuf[buf][0] + tid * 16);
    };

    // acc[r][i][p]: p=0 -> chains (j0,j1), p=1 -> chains (j2,j3)
    f32x2 acc[4][4][2];
#pragma unroll
    for (int r = 0; r < 4; ++r)
#pragma unroll
        for (int i = 0; i < 4; ++i)
#pragma unroll
            for (int p = 0; p < 2; ++p) acc[r][i][p] = (f32x2){0.0f, 0.0f};

    auto compute = [&](int buf) {
#pragma unroll
        for (int c = 3; c >= 0; --c) {          // reversed chunk order in 16-group
            f32x2 xlo[4], xhi[4];
#pragma unroll
            for (int r = 0; r < 4; ++r) {
                const float4 xv = *(const float4*)&xbuf[buf][(r0 + r) * BK + c * 4];
                xlo[r] = (f32x2){xv.x, xv.y};
                xhi[r] = (f32x2){xv.z, xv.w};
            }
            __builtin_amdgcn_s_setprio(1);
#pragma unroll
            for (int i = 0; i < 4; ++i) {
                const float4 wv = *(const float4*)&wbuf[buf][(c * 256 + elane + 64 * i) * 4];
                const f32x2 wlo = (f32x2){wv.x, wv.y};
                const f32x2 whi = (f32x2){wv.z, wv.w};
#pragma unroll
                for (int r = 0; r < 4; ++r) {
                    acc[r][i][0] = pkadd(acc[r][i][0], pkmul(xlo[r], wlo));
                    acc[r][i][1] = pkadd(acc[r][i][1], pkmul(xhi[r], whi));
                }
            }
            __builtin_amdgcn_s_setprio(0);
        }
    };

    // ---- main loop: double-buffered global_load_lds pipeline ----
    stage(0, 0);
    __syncthreads();
    for (int kt = 0; kt < NTILE; ++kt) {
        const int buf = kt & 1;
        if (kt + 1 < NTILE) stage(buf ^ 1, kt + 1);
        compute(buf);
        __syncthreads();
    }

    // ---- epilogue: hadd tree + f64 sigmoid -> scores in wbuf[0] ----
    float* sc = &wbuf[0][0];                 // [16][256] = 16 KB (exact fit)
#pragma unroll
    for (int r = 0; r < 4; ++r)
#pragma unroll
        for (int i = 0; i < 4; ++i) {
            const float l01 = acc[r][i][0].x + acc[r][i][0].y;
            const float l23 = acc[r][i][1].x + acc[r][i][1].y;
            const float logit = l01 + l23;
            const double s = 1.0 / (1.0 + exp(-(double)logit));
            sc[(r0 + r) * NEXP + (elane + 64 * i)] = (float)s;
        }
    __syncthreads();

    float* cval = &wbuf[1][0];               // [16][64]
    int*   cidx = (int*)&wbuf[1][1024];      // [16][64]

    // ---- per-row top-8: 8 subs/row on first 128 threads ----
    if (tid < 128) {
        const int row = tid >> 3;
        const int sub = tid & 7;
        float tv[TOPK];
        int   ti[TOPK];
#pragma unroll
        for (int q = 0; q < TOPK; ++q) { tv[q] = -INFINITY; ti[q] = INT_MAX; }
        for (int j = 0; j < 32; ++j) {
            const int e = sub + (j << 3);    // ascending index => stable
            const float v = sc[row * NEXP + e] + bias[e];
            if (v > tv[TOPK - 1]) {
                int p = TOPK - 1;
                while (p > 0 && v > tv[p - 1]) {
                    tv[p] = tv[p - 1]; ti[p] = ti[p - 1]; --p;
                }
                tv[p] = v; ti[p] = e;
            }
        }
#pragma unroll
        for (int q = 0; q < TOPK; ++q) {
            cval[row * 64 + sub * 8 + q] = tv[q];
            cidx[row * 64 + sub * 8 + q] = ti[q];
        }
    }
    __syncthreads();

    // ---- leaders merge 8 sorted lists; ties -> lower index; output ----
    if (tid < 128 && (tid & 7) == 0) {
        const int row = tid >> 3;
        int p[8];
#pragma unroll
        for (int s = 0; s < 8; ++s) p[s] = 0;
        float g[TOPK];
        int   sel[TOPK];
        for (int k = 0; k < TOPK; ++k) {
            float best = -INFINITY;
            int bidx = INT_MAX;
            int bs = 0;
            for (int s = 0; s < 8; ++s) {
                if (p[s] < 8) {
                    const float v = cval[row * 64 + s * 8 + p[s]];
                    const int  id = cidx[row * 64 + s * 8 + p[s]];
                    if (v > best || (v == best && id < bidx)) {
                        best = v; bidx = id; bs = s;
                    }
                }
            }
            p[bs]++;
            sel[k] = bidx;
            g[k] = sc[row * NEXP + bidx];    // original score (no bias)
        }
        const float s01 = g[0] + g[1], s23 = g[2] + g[3];
        const float s45 = g[4] + g[5], s67 = g[6] + g[7];
        const float wsum = (s01 + s23) + (s45 + s67);
        const float den = wsum + 1e-20f;
        const size_t orow = (size_t)(gr + row) * TOPK;
#pragma unroll
        for (int k = 0; k < TOPK; ++k) {
            outw[orow + k] = (g[k] / den) * 2.5f;
            outi[orow + k] = (float)sel[k];
        }
    }
}

extern "C" void kernel_launch(void* const* d_in, const int* in_sizes, int n_in,
                              void* d_out, int out_size, void* d_ws, size_t ws_size,
                              hipStream_t stream) {
    const float* x    = (const float*)d_in[0];
    const float* w    = (const float*)d_in[1];
    const float* bias = (const float*)d_in[2];
    float* outw = (float*)d_out;
    const int M = in_sizes[0] / DIM;              // 16384 rows
    float* outi = outw + (size_t)M * TOPK;
    const int grid = M / BM;                      // 1024 blocks
    hipLaunchKernelGGL(gate_kernel, dim3(grid), dim3(NTH), 0, stream,
                       x, w, bias, outw, outi);
}

// Round 12
// 395.310 us; speedup vs baseline: 1.8503x; 1.0480x over previous
//
#include <hip/hip_runtime.h>
#include <math.h>
#include <limits.h>

#define DIM 2048
#define NEXP 256
#define TOPK 8
#define BM 32
#define BK 16
#define NTH 512
#define NTILE 128

// np-einsum fp32 replica (LOCKED by R3/R4/R6/R8/R11 passes — do not perturb):
//   4 partial chains per output, chain j takes k ≡ j (mod 4);
//   k in 16-groups ascending, within group chunk order 3,2,1,0;
//   separate mul/add rounding (no fma); hadd tree (l0+l1)+(l2+l3);
//   sigmoid in f64 -> f32; pairwise-8 weight sum; ties -> lower index.
// v_pk_*_f32 = element-wise IEEE f32 (bit-identical, halves issue slots).
// R12: BM=32 / 512 threads / 8 waves — same per-wave tile (4 rows x 256
// experts, identical chain), doubled waves/SIMD for latency hiding.
// Keep: setprio (R11 +11%), plain __syncthreads dbuf (R9/R10 lessons).

typedef float f32x2 __attribute__((ext_vector_type(2)));

__device__ __forceinline__ f32x2 pkmul(f32x2 a, f32x2 b) {
    f32x2 d;
    asm("v_pk_mul_f32 %0, %1, %2" : "=v"(d) : "v"(a), "v"(b));
    return d;
}
__device__ __forceinline__ f32x2 pkadd(f32x2 a, f32x2 b) {
    f32x2 d;
    asm("v_pk_add_f32 %0, %1, %2" : "=v"(d) : "v"(a), "v"(b));
    return d;
}

__device__ __forceinline__ void gload16(const void* gptr, void* lptr) {
    __builtin_amdgcn_global_load_lds(
        (const __attribute__((address_space(1))) unsigned int*)(unsigned long long)gptr,
        (__attribute__((address_space(3))) unsigned int*)(unsigned int)(unsigned long long)lptr,
        16, 0, 0);
}

__global__ __launch_bounds__(NTH) void gate_kernel(
    const float* __restrict__ x, const float* __restrict__ w,
    const float* __restrict__ bias, float* __restrict__ outw,
    float* __restrict__ outi)
{
#pragma clang fp contract(off)
    // wbuf[buf]: float idx (c*256 + e)*4 + j  (chunk c=0..3, expert e, j=k%4)
    __shared__ float wbuf[2][4096];   // 32 KB
    __shared__ float xbuf[2][512];    // 4 KB  [row*16 + k]

    const int tid   = threadIdx.x;
    const int elane = tid & 63;              // experts elane + 64*i
    const int r0    = (tid >> 6) * 4;        // 4 rows per wave, 8 waves = 32 rows
    const int gr    = blockIdx.x * BM;

    // ---- staging: w by (expert, chunk-half), x by first 128 threads ----
    const int we    = tid & 255;             // expert row this thread stages
    const int chalf = tid >> 8;              // 0 -> chunks 0,1 ; 1 -> chunks 2,3
    const char* wbase = (const char*)w + (size_t)we * (DIM * 4);
    const int xrow = tid >> 2, xq = tid & 3;                 // tid<128 stages x
    const char* xbase = (const char*)x + ((size_t)(gr + xrow) * DIM + xq * 4) * 4;

    auto stage = [&](int buf, int kt) {
        const size_t kb = (size_t)kt * 64;   // 16 floats = 64 B per tile
        char* dst = (char*)&wbuf[buf][0] + we * 16;
        const int c0 = chalf * 2;
        gload16(wbase + kb + c0 * 16,        dst + c0 * 4096);
        gload16(wbase + kb + (c0 + 1) * 16,  dst + (c0 + 1) * 4096);
        if (tid < 128)
            gload16(xbase + kb, (char*)&xbuf[buf][0] + tid * 16);
    };

    // acc[r][i][p]: p=0 -> chains (j0,j1), p=1 -> chains (j2,j3)
    f32x2 acc[4][4][2];
#pragma unroll
    for (int r = 0; r < 4; ++r)
#pragma unroll
        for (int i = 0; i < 4; ++i)
#pragma unroll
            for (int p = 0; p < 2; ++p) acc[r][i][p] = (f32x2){0.0f, 0.0f};

    auto compute = [&](int buf) {
#pragma unroll
        for (int c = 3; c >= 0; --c) {          // reversed chunk order in 16-group
            f32x2 xlo[4], xhi[4];
#pragma unroll
            for (int r = 0; r < 4; ++r) {
                const float4 xv = *(const float4*)&xbuf[buf][(r0 + r) * BK + c * 4];
                xlo[r] = (f32x2){xv.x, xv.y};
                xhi[r] = (f32x2){xv.z, xv.w};
            }
            __builtin_amdgcn_s_setprio(1);
#pragma unroll
            for (int i = 0; i < 4; ++i) {
                const float4 wv = *(const float4*)&wbuf[buf][(c * 256 + elane + 64 * i) * 4];
                const f32x2 wlo = (f32x2){wv.x, wv.y};
                const f32x2 whi = (f32x2){wv.z, wv.w};
#pragma unroll
                for (int r = 0; r < 4; ++r) {
                    acc[r][i][0] = pkadd(acc[r][i][0], pkmul(xlo[r], wlo));
                    acc[r][i][1] = pkadd(acc[r][i][1], pkmul(xhi[r], whi));
                }
            }
            __builtin_amdgcn_s_setprio(0);
        }
    };

    // ---- main loop: double-buffered global_load_lds pipeline ----
    stage(0, 0);
    __syncthreads();
    for (int kt = 0; kt < NTILE; ++kt) {
        const int buf = kt & 1;
        if (kt + 1 < NTILE) stage(buf ^ 1, kt + 1);
        compute(buf);
        __syncthreads();
    }

    // ---- epilogue: hadd tree + f64 sigmoid -> scores fill ALL of wbuf ----
    float* sc = &wbuf[0][0];                 // [32][256] = 32 KB (exact fit)
#pragma unroll
    for (int r = 0; r < 4; ++r)
#pragma unroll
        for (int i = 0; i < 4; ++i) {
            const float l01 = acc[r][i][0].x + acc[r][i][0].y;
            const float l23 = acc[r][i][1].x + acc[r][i][1].y;
            const float logit = l01 + l23;
            const double s = 1.0 / (1.0 + exp(-(double)logit));
            sc[(r0 + r) * NEXP + (elane + 64 * i)] = (float)s;
        }
    __syncthreads();

    float* cval = &xbuf[0][0];               // [32][16]  (2 subs x top-8)
    int*   cidx = (int*)&xbuf[1][0];         // [32][16]

    // ---- per-row top-8: 2 subs/row on first 64 threads (128 experts each) ----
    if (tid < 64) {
        const int row = tid >> 1;
        const int sub = tid & 1;
        float tv[TOPK];
        int   ti[TOPK];
#pragma unroll
        for (int q = 0; q < TOPK; ++q) { tv[q] = -INFINITY; ti[q] = INT_MAX; }
        for (int j = 0; j < 128; ++j) {
            const int e = sub + (j << 1);    // ascending index => stable
            const float v = sc[row * NEXP + e] + bias[e];
            if (v > tv[TOPK - 1]) {
                int p = TOPK - 1;
                while (p > 0 && v > tv[p - 1]) {
                    tv[p] = tv[p - 1]; ti[p] = ti[p - 1]; --p;
                }
                tv[p] = v; ti[p] = e;
            }
        }
#pragma unroll
        for (int q = 0; q < TOPK; ++q) {
            cval[row * 16 + sub * 8 + q] = tv[q];
            cidx[row * 16 + sub * 8 + q] = ti[q];
        }
    }
    __syncthreads();

    // ---- leaders (32 threads) merge 2 sorted lists; ties -> lower index ----
    if (tid < 32) {
        const int row = tid;
        int p0 = 0, p1 = 0;
        float g[TOPK];
        int   sel[TOPK];
#pragma unroll
        for (int k = 0; k < TOPK; ++k) {
            const float v0 = cval[row * 16 + p0];
            const int   i0 = cidx[row * 16 + p0];
            const float v1 = cval[row * 16 + 8 + p1];
            const int   i1 = cidx[row * 16 + 8 + p1];
            int take0;
            if (v0 > v1) take0 = 1;
            else if (v1 > v0) take0 = 0;
            else take0 = (i0 < i1);
            const int e = take0 ? i0 : i1;
            p0 += take0; p1 += 1 - take0;
            sel[k] = e;
            g[k] = sc[row * NEXP + e];       // original score (no bias)
        }
        const float s01 = g[0] + g[1], s23 = g[2] + g[3];
        const float s45 = g[4] + g[5], s67 = g[6] + g[7];
        const float wsum = (s01 + s23) + (s45 + s67);
        const float den = wsum + 1e-20f;
        const size_t orow = (size_t)(gr + row) * TOPK;
#pragma unroll
        for (int k = 0; k < TOPK; ++k) {
            outw[orow + k] = (g[k] / den) * 2.5f;
            outi[orow + k] = (float)sel[k];
        }
    }
}

extern "C" void kernel_launch(void* const* d_in, const int* in_sizes, int n_in,
                              void* d_out, int out_size, void* d_ws, size_t ws_size,
                              hipStream_t stream) {
    const float* x    = (const float*)d_in[0];
    const float* w    = (const float*)d_in[1];
    const float* bias = (const float*)d_in[2];
    float* outw = (float*)d_out;
    const int M = in_sizes[0] / DIM;              // 16384 rows
    float* outi = outw + (size_t)M * TOPK;
    const int grid = M / BM;                      // 512 blocks
    hipLaunchKernelGGL(gate_kernel, dim3(grid), dim3(NTH), 0, stream,
                       x, w, bias, outw, outi);
}